// Round 5
// baseline (470.260 us; speedup 1.0000x reference)
//
#include <hip/hip_runtime.h>
#include <math.h>
#include <utility>

// ---------------------------------------------------------------------------
// FCTP(64x0e+32x1o+16x2e -> 64x0e) + 3-layer SiLU MLP, fwd + input-grad.
//   fwd: h = P[N,2880pad] @ Weff[2880,64], P computed in-registers (static pairs)
//   bwd: dP^T = Wb_chunk[64pair,64ch] @ dh^T[64ch,64s], per-sample row-dot vs x
// Round 5: 4 waves/block over the SAME 64 samples, chunk list split across
// waves (K-split) -> 3128 waves (~3/SIMD) instead of 782 (~0.76/SIMD).
// Wave-private LDS buffers + in-wave s_waitcnt ordering -> no barriers in the
// chunk loops. fwd ends with a 4-barrier cross-wave C reduction in LDS.
// ---------------------------------------------------------------------------

typedef short bf8 __attribute__((ext_vector_type(8)));
typedef float f4 __attribute__((ext_vector_type(4)));
typedef unsigned int u32;

constexpr int IRR = 240;
constexpr int NP = 2880;   // padded fwd pairs: l0 [0,2112) real 2080; l1 [2112,2688) real 528; l2 [2688,2880) real 136

struct PTab { short u[NP]; short v[NP]; signed char l[NP]; };
constexpr PTab build_ptab() {
    PTab t{}; int p = 0;
    for (int u = 0; u < 64; u++) for (int v = u; v < 64; v++) { t.u[p]=(short)u; t.v[p]=(short)v; t.l[p]=0; p++; }
    while (p < 2112) { t.l[p] = -1; p++; }
    for (int u = 0; u < 32; u++) for (int v = u; v < 32; v++) { t.u[p]=(short)u; t.v[p]=(short)v; t.l[p]=1; p++; }
    while (p < 2688) { t.l[p] = -1; p++; }
    for (int u = 0; u < 16; u++) for (int v = u; v < 16; v++) { t.u[p]=(short)u; t.v[p]=(short)v; t.l[p]=2; p++; }
    while (p < NP)   { t.l[p] = -1; p++; }
    return t;
}
constexpr PTab PT = build_ptab();

// ws layout (bytes)
constexpr size_t B_WTF = 0;                       // bf16 [64 chan][2880 pair]
constexpr size_t B_WB  = (size_t)64 * NP * 2;     // bf16 [5376 pair][64 chan]
constexpr size_t B_A1T = B_WB + (size_t)5376 * 64 * 2;
constexpr size_t B_A2T = B_A1T + 16384;
constexpr size_t B_A3T = B_A2T + 16384;
constexpr size_t B_DG2 = B_A3T + 16384;
constexpr size_t B_H   = B_DG2 + 256;

__device__ __forceinline__ unsigned short f2bf(float x) {
    unsigned int u = __float_as_uint(x);
    return (unsigned short)((u + 0x7fffu + ((u >> 16) & 1u)) >> 16);
}
__device__ __forceinline__ unsigned pack2(float a, float b) {   // -> [bf16(a) lo, bf16(b) hi]
    unsigned ua = __float_as_uint(a) + 0x8000u;
    unsigned ub = __float_as_uint(b) + 0x8000u;
    return __builtin_amdgcn_perm(ub, ua, 0x07060302u);
}
__device__ __forceinline__ float blo(u32 u) { return __uint_as_float(u << 16); }
__device__ __forceinline__ float bhi(u32 u) { return __uint_as_float(u & 0xffff0000u); }

// in-wave LDS write->read ordering (same-wave DS ops execute in order; the
// waitcnt guarantees completion, the clobber pins compiler order)
#define LGKM_SYNC() asm volatile("s_waitcnt lgkmcnt(0)" ::: "memory")
#define MEM_ORDER() asm volatile("" ::: "memory")

// ---------------------------------------------------------------------------
__global__ void prep_kernel(const float* __restrict__ W0, const float* __restrict__ W1,
                            const float* __restrict__ W2, const float* __restrict__ A1,
                            const float* __restrict__ A2, const float* __restrict__ A3,
                            unsigned short* __restrict__ wtf, unsigned short* __restrict__ wb,
                            float* __restrict__ a1t, float* __restrict__ a2t,
                            float* __restrict__ a3t, float* __restrict__ dg2)
{
    int idx = blockIdx.x * blockDim.x + threadIdx.x;
    const double c0 = 1.0 / sqrt(5376.0);
    const double cl_[3] = { c0, c0 / sqrt(3.0), c0 / sqrt(5.0) };
    if (idx < 64 * NP) {
        int c = idx / NP, p = idx - c * NP;
        unsigned short val = 0;
        int l = -1, local = 0, mul = 0;
        if (p < 2112)      { local = p;        if (local < 2080) { l = 0; mul = 64; } }
        else if (p < 2688) { local = p - 2112; if (local < 528)  { l = 1; mul = 32; } }
        else               { local = p - 2688; if (local < 136)  { l = 2; mul = 16; } }
        if (l >= 0) {
            int u = 0;
            while ((u + 1) * mul - (u + 1) * u / 2 <= local) u++;
            int v = u + (local - (u * mul - u * (u - 1) / 2));
            const float* W = (l == 0) ? W0 : (l == 1) ? W1 : W2;
            float wv = W[(u * mul + v) * 64 + c];
            if (u != v) wv += W[(v * mul + u) * 64 + c];
            val = f2bf((float)(cl_[l] * wv));
        }
        wtf[(size_t)c * NP + p] = val;
        return;
    }
    idx -= 64 * NP;
    if (idx < 5376 * 64) {
        int pair = idx >> 6, c = idx & 63;
        int l, w, v, mul;
        if (pair < 4096)      { l = 0; mul = 64; w = pair >> 6;          v = pair & 63; }
        else if (pair < 5120) { l = 1; mul = 32; w = (pair - 4096) >> 5; v = (pair - 4096) & 31; }
        else                  { l = 2; mul = 16; w = (pair - 5120) >> 4; v = (pair - 5120) & 15; }
        const float* W = (l == 0) ? W0 : (l == 1) ? W1 : W2;
        float val;
        if (v == w) val = (float)(2.0 * cl_[l]) * W[(w * mul + w) * 64 + c];
        else        val = (float)cl_[l] * (W[(w * mul + v) * 64 + c] + W[(v * mul + w) * 64 + c]);
        wb[(size_t)pair * 64 + c] = f2bf(val);
        return;
    }
    idx -= 5376 * 64;
    if (idx < 3 * 4096) {
        int m = idx >> 12, e = idx & 4095;
        int j = e >> 6, k = e & 63;
        const float* A = (m == 0) ? A1 : (m == 1) ? A2 : A3;
        float* dst     = (m == 0) ? a1t : (m == 1) ? a2t : a3t;
        dst[j * 64 + k] = A[k * 64 + j];
        return;
    }
    idx -= 3 * 4096;
    if (idx < 64) {
        float s = 0.f;
        for (int k = 0; k < 64; k++) s += A3[k * 64 + idx];
        dg2[idx] = s;
    }
}

// ---------------------------------------------------------------------------
// forward machinery (compile-time pair table)
// ---------------------------------------------------------------------------
template <int P, int NX>
__device__ __forceinline__ float pval(const float (&x)[NX]) {
    constexpr int l = PT.l[P];
    if constexpr (l < 0) {
        return 0.f;
    } else if constexpr (l == 0) {
        return x[PT.u[P]] * x[PT.v[P]];
    } else if constexpr (l == 1) {
        constexpr int u = 3 * PT.u[P], v = 3 * PT.v[P];
        return x[u] * x[v] + x[u + 1] * x[v + 1] + x[u + 2] * x[v + 2];
    } else {
        constexpr int u = 5 * PT.u[P], v = 5 * PT.v[P];
        return x[u] * x[v] + x[u + 1] * x[v + 1] + x[u + 2] * x[v + 2]
             + x[u + 3] * x[v + 3] + x[u + 4] * x[v + 4];
    }
}

template <int CH, int O, int NX>
__device__ __forceinline__ void p_octet(const float (&xr)[NX],
        unsigned short (&Pb)[64][64], int lane)
{
    uint4 w;
    w.x = pack2(pval<CH * 64 + O * 8 + 0, NX>(xr), pval<CH * 64 + O * 8 + 1, NX>(xr));
    w.y = pack2(pval<CH * 64 + O * 8 + 2, NX>(xr), pval<CH * 64 + O * 8 + 3, NX>(xr));
    w.z = pack2(pval<CH * 64 + O * 8 + 4, NX>(xr), pval<CH * 64 + O * 8 + 5, NX>(xr));
    w.w = pack2(pval<CH * 64 + O * 8 + 6, NX>(xr), pval<CH * 64 + O * 8 + 7, NX>(xr));
    *(uint4*)&Pb[lane][(O ^ (lane & 7)) * 8] = w;
}

template <int CH, int NX, int... Os>
__device__ __forceinline__ void p_octets(std::integer_sequence<int, Os...>,
        const float (&xr)[NX], unsigned short (&Pb)[64][64], int lane)
{
    (p_octet<CH, Os, NX>(xr, Pb, lane), ...);
}

template <int CH, int NX>
__device__ __forceinline__ void fwd_chunk(const float (&xr)[NX],
        unsigned short (&Pb)[64][64], const unsigned short* __restrict__ wtf,
        f4 (&acc)[4][4], int lane, int l15, int quad)
{
    p_octets<CH, NX>(std::make_integer_sequence<int, 8>{}, xr, Pb, lane);
    LGKM_SYNC();
    bf8 a[4][2];
    #pragma unroll
    for (int rt = 0; rt < 4; ++rt) {
        int row = 16 * rt + l15;
        #pragma unroll
        for (int ks = 0; ks < 2; ++ks)
            a[rt][ks] = *(const bf8*)&Pb[row][((ks * 4 + quad) ^ (row & 7)) * 8];
    }
    #pragma unroll
    for (int ct = 0; ct < 4; ++ct) {
        #pragma unroll
        for (int ks = 0; ks < 2; ++ks) {
            bf8 b = *(const bf8*)(wtf + (size_t)(16 * ct + l15) * NP + CH * 64 + ks * 32 + quad * 8);
            #pragma unroll
            for (int rt = 0; rt < 4; ++rt)
                acc[rt][ct] = __builtin_amdgcn_mfma_f32_16x16x32_bf16(a[rt][ks], b, acc[rt][ct], 0, 0, 0);
        }
    }
    MEM_ORDER();   // WAR vs next chunk's Pb writes (in-wave DS order)
}

template <int B, int NX, int... Is>
__device__ __forceinline__ void fwd_run(std::integer_sequence<int, Is...>,
        const float (&xr)[NX], unsigned short (&Pb)[64][64],
        const unsigned short* __restrict__ wtf, f4 (&acc)[4][4],
        int lane, int l15, int quad)
{
    (fwd_chunk<B + Is, NX>(xr, Pb, wtf, acc, lane, l15, quad), ...);
}

__global__ __launch_bounds__(256) void fctp_fwd(const float* __restrict__ tin,
        const unsigned short* __restrict__ wtf, float* __restrict__ h, int n)
{
    __shared__ unsigned short Pb[4][64][64];   // per-wave P staging (32 KB)
    __shared__ float Cred[64][68];             // [chan][sample] reduction (17.4 KB)
    const int tid = threadIdx.x;
    const int wv = tid >> 6, lane = tid & 63;
    const int l15 = lane & 15, quad = lane >> 4;
    const int s0 = blockIdx.x * 64;
    const int s = s0 + lane;
    const int sld = (s < n) ? s : (n - 1);
    const float* xrow = tin + (size_t)sld * IRR;
    unsigned short (&Pw)[64][64] = Pb[wv];
    f4 acc[4][4];
    #pragma unroll
    for (int rt = 0; rt < 4; ++rt)
        #pragma unroll
        for (int ct = 0; ct < 4; ++ct) acc[rt][ct] = (f4){0.f, 0.f, 0.f, 0.f};
    // chunk split (FLOP-balanced): w0: l0 0-13 | w1: l0 14-27 | w2: l0 28-32 + l1 33-35
    // | w3: l1 36-41 + l2 42-44
    if (wv == 0) {
        float x0[64];
        #pragma unroll
        for (int q = 0; q < 16; ++q) *(float4*)&x0[4 * q] = *(const float4*)(xrow + 4 * q);
        fwd_run<0>(std::make_integer_sequence<int, 14>{}, x0, Pw, wtf, acc, lane, l15, quad);
    } else if (wv == 1) {
        float x0[64];
        #pragma unroll
        for (int q = 0; q < 16; ++q) *(float4*)&x0[4 * q] = *(const float4*)(xrow + 4 * q);
        fwd_run<14>(std::make_integer_sequence<int, 14>{}, x0, Pw, wtf, acc, lane, l15, quad);
    } else if (wv == 2) {
        {
            float x0[64];
            #pragma unroll
            for (int q = 0; q < 16; ++q) *(float4*)&x0[4 * q] = *(const float4*)(xrow + 4 * q);
            fwd_run<28>(std::make_integer_sequence<int, 5>{}, x0, Pw, wtf, acc, lane, l15, quad);
        }
        {
            float x1[96];
            #pragma unroll
            for (int q = 0; q < 24; ++q) *(float4*)&x1[4 * q] = *(const float4*)(xrow + 64 + 4 * q);
            fwd_run<33>(std::make_integer_sequence<int, 3>{}, x1, Pw, wtf, acc, lane, l15, quad);
        }
    } else {
        {
            float x1[96];
            #pragma unroll
            for (int q = 0; q < 24; ++q) *(float4*)&x1[4 * q] = *(const float4*)(xrow + 64 + 4 * q);
            fwd_run<36>(std::make_integer_sequence<int, 6>{}, x1, Pw, wtf, acc, lane, l15, quad);
        }
        {
            float x2[80];
            #pragma unroll
            for (int q = 0; q < 20; ++q) *(float4*)&x2[4 * q] = *(const float4*)(xrow + 160 + 4 * q);
            fwd_run<42>(std::make_integer_sequence<int, 3>{}, x2, Pw, wtf, acc, lane, l15, quad);
        }
    }
    // cross-wave C reduction: Cred[chan=16ct+l15][sample=16rt+4quad+r]
    for (int w = 0; w < 4; ++w) {
        if (wv == w) {
            #pragma unroll
            for (int rt = 0; rt < 4; ++rt)
                #pragma unroll
                for (int ct = 0; ct < 4; ++ct) {
                    f4* p = (f4*)&Cred[16 * ct + l15][16 * rt + 4 * quad];
                    if (w == 0) *p = acc[rt][ct];
                    else        *p = *p + acc[rt][ct];
                }
        }
        __syncthreads();
    }
    // store h[sample][chan], coalesced (16 threads per sample row)
    for (int q = tid; q < 1024; q += 256) {
        int smp = q >> 4, c4 = (q & 15) * 4;
        if (s0 + smp < n) {
            float4 v = make_float4(Cred[c4][smp], Cred[c4 + 1][smp],
                                   Cred[c4 + 2][smp], Cred[c4 + 3][smp]);
            *(float4*)(h + (size_t)(s0 + smp) * 64 + c4) = v;
        }
    }
}

// ---------------------------------------------------------------------------
// backward: dP^T = Wb_chunk @ dh^T ; per-wave bf16 dP staging, consume with
// x in fp32 regs (compile-time indices via unrolled k/e loops).
// ---------------------------------------------------------------------------
__device__ __forceinline__ void bwd_mm(int ch, const unsigned short* __restrict__ wb,
        const bf8 (&bh)[4][2], u32 (&dPw)[64][34], uint2 (&d)[16],
        int lane, int l15, int quad)
{
    f4 dp[4][4];
    #pragma unroll
    for (int rt = 0; rt < 4; ++rt)
        #pragma unroll
        for (int ct = 0; ct < 4; ++ct) dp[rt][ct] = (f4){0.f, 0.f, 0.f, 0.f};
    #pragma unroll
    for (int rt = 0; rt < 4; ++rt) {
        #pragma unroll
        for (int ks = 0; ks < 2; ++ks) {
            bf8 a = *(const bf8*)(wb + (size_t)(ch * 64 + 16 * rt + l15) * 64 + ks * 32 + quad * 8);
            #pragma unroll
            for (int ct = 0; ct < 4; ++ct)
                dp[rt][ct] = __builtin_amdgcn_mfma_f32_16x16x32_bf16(a, bh[ct][ks], dp[rt][ct], 0, 0, 0);
        }
    }
    // dp[rt][ct][r] = dP^T[pair=16rt+4quad+r][sample=16ct+l15] -> dPw[sample][pair/2] bf16-packed
    #pragma unroll
    for (int rt = 0; rt < 4; ++rt)
        #pragma unroll
        for (int ct = 0; ct < 4; ++ct) {
            uint2 w;
            w.x = pack2(dp[rt][ct][0], dp[rt][ct][1]);
            w.y = pack2(dp[rt][ct][2], dp[rt][ct][3]);
            *(uint2*)&dPw[16 * ct + l15][8 * rt + 2 * quad] = w;
        }
    LGKM_SYNC();
    #pragma unroll
    for (int k = 0; k < 16; ++k) d[k] = *(const uint2*)&dPw[lane][2 * k];
    MEM_ORDER();
}

__device__ __forceinline__ void consume_l0(const uint2 (&d)[16], const float (&x0)[64],
        int ch, bool act, float* __restrict__ yrow)
{
    float a0 = 0.f, a1 = 0.f, a2 = 0.f, a3 = 0.f;
    #pragma unroll
    for (int k = 0; k < 16; ++k) {
        a0 += blo(d[k].x) * x0[4 * k + 0];
        a1 += bhi(d[k].x) * x0[4 * k + 1];
        a2 += blo(d[k].y) * x0[4 * k + 2];
        a3 += bhi(d[k].y) * x0[4 * k + 3];
    }
    if (act) yrow[ch] = (a0 + a1) + (a2 + a3);
}

__device__ __forceinline__ void consume_l1(const uint2 (&d)[16], const float (&x1)[96],
        int c1, bool act, float* __restrict__ yrow)
{
    float r[2][3] = {{0.f, 0.f, 0.f}, {0.f, 0.f, 0.f}};
    #pragma unroll
    for (int k = 0; k < 16; ++k) {
        #pragma unroll
        for (int e = 0; e < 2; ++e) {
            u32 u = e ? d[k].y : d[k].x;
            const int p0 = 4 * k + 2 * e;
            float f0 = blo(u), f1 = bhi(u);
            const int w0 = p0 >> 5, v0 = p0 & 31, v1 = (p0 + 1) & 31;
            r[w0][0] += f0 * x1[3 * v0 + 0] + f1 * x1[3 * v1 + 0];
            r[w0][1] += f0 * x1[3 * v0 + 1] + f1 * x1[3 * v1 + 1];
            r[w0][2] += f0 * x1[3 * v0 + 2] + f1 * x1[3 * v1 + 2];
        }
    }
    if (act) {
        #pragma unroll
        for (int wi = 0; wi < 2; ++wi)
            #pragma unroll
            for (int m = 0; m < 3; ++m)
                yrow[64 + (2 * c1 + wi) * 3 + m] = r[wi][m];
    }
}

__device__ __forceinline__ void consume_l2(const uint2 (&d)[16], const float (&x2)[80],
        int c2, bool act, float* __restrict__ yrow)
{
    float r[4][5] = {};
    #pragma unroll
    for (int k = 0; k < 16; ++k) {
        #pragma unroll
        for (int e = 0; e < 2; ++e) {
            u32 u = e ? d[k].y : d[k].x;
            const int p0 = 4 * k + 2 * e;
            float f0 = blo(u), f1 = bhi(u);
            const int t0 = p0 >> 4, v0 = p0 & 15;
            const int t1 = (p0 + 1) >> 4, v1 = (p0 + 1) & 15;
            #pragma unroll
            for (int m = 0; m < 5; ++m) {
                r[t0][m] += f0 * x2[5 * v0 + m];
                r[t1][m] += f1 * x2[5 * v1 + m];
            }
        }
    }
    if (act) {
        #pragma unroll
        for (int t = 0; t < 4; ++t)
            #pragma unroll
            for (int m = 0; m < 5; ++m)
                yrow[160 + (4 * c2 + t) * 5 + m] = r[t][m];
    }
}

__global__ __launch_bounds__(256) void fctp_bwd(const float* __restrict__ tin,
        const unsigned short* __restrict__ wb, const float* __restrict__ dh,
        float* __restrict__ y, int n)
{
    __shared__ unsigned short dhb[64][64];     // 8 KB, shared read-only
    __shared__ u32 dPb[4][64][34];             // per-wave bf16 dP rows (34.8 KB)
    const int tid = threadIdx.x;
    const int wv = tid >> 6, lane = tid & 63;
    const int l15 = lane & 15, quad = lane >> 4;
    const int s0 = blockIdx.x * 64;
    const int s = s0 + lane;
    const int sld = (s < n) ? s : (n - 1);
    const bool act = s < n;
    // stage dh -> bf16 (octet-swizzled), 256 threads: 2 octets each
    {
        int ss = tid & 63;
        int sld2 = (s0 + ss < n) ? (s0 + ss) : (n - 1);
        const float* dhp = dh + (size_t)sld2 * 64;
        int ob = (tid >> 6) * 2;
        #pragma unroll
        for (int it = 0; it < 2; ++it) {
            int o = ob + it;
            float4 f0 = *(const float4*)(dhp + 8 * o);
            float4 f1 = *(const float4*)(dhp + 8 * o + 4);
            uint4 w = make_uint4(pack2(f0.x, f0.y), pack2(f0.z, f0.w),
                                 pack2(f1.x, f1.y), pack2(f1.z, f1.w));
            *(uint4*)&dhb[ss][(o ^ (ss & 7)) * 8] = w;
        }
    }
    __syncthreads();
    // persistent B-frags (dh^T): B[k=chan][col=sample]
    bf8 bh[4][2];
    #pragma unroll
    for (int ct = 0; ct < 4; ++ct) {
        int row = 16 * ct + l15;
        #pragma unroll
        for (int ks = 0; ks < 2; ++ks)
            bh[ct][ks] = *(const bf8*)&dhb[row][((ks * 4 + quad) ^ (row & 7)) * 8];
    }
    u32 (&dPw)[64][34] = dPb[wv];
    const float* xrow = tin + (size_t)sld * IRR;
    float* yrow = y + (size_t)sld * IRR;
    uint2 d[16];
    // chunk split: w0: l0 0-23 | w1: l0 24-47 | w2: l0 48-63 + l1 0-3 | w3: l1 4-15 + l2 0-3
    if (wv <= 1) {
        float x0[64];
        #pragma unroll
        for (int q = 0; q < 16; ++q) *(float4*)&x0[4 * q] = *(const float4*)(xrow + 4 * q);
        const int c0 = wv * 24;
        for (int ch = c0; ch < c0 + 24; ++ch) {
            bwd_mm(ch, wb, bh, dPw, d, lane, l15, quad);
            consume_l0(d, x0, ch, act, yrow);
        }
    } else if (wv == 2) {
        {
            float x0[64];
            #pragma unroll
            for (int q = 0; q < 16; ++q) *(float4*)&x0[4 * q] = *(const float4*)(xrow + 4 * q);
            for (int ch = 48; ch < 64; ++ch) {
                bwd_mm(ch, wb, bh, dPw, d, lane, l15, quad);
                consume_l0(d, x0, ch, act, yrow);
            }
        }
        {
            float x1[96];
            #pragma unroll
            for (int q = 0; q < 24; ++q) *(float4*)&x1[4 * q] = *(const float4*)(xrow + 64 + 4 * q);
            for (int c1 = 0; c1 < 4; ++c1) {
                bwd_mm(64 + c1, wb, bh, dPw, d, lane, l15, quad);
                consume_l1(d, x1, c1, act, yrow);
            }
        }
    } else {
        {
            float x1[96];
            #pragma unroll
            for (int q = 0; q < 24; ++q) *(float4*)&x1[4 * q] = *(const float4*)(xrow + 64 + 4 * q);
            for (int c1 = 4; c1 < 16; ++c1) {
                bwd_mm(64 + c1, wb, bh, dPw, d, lane, l15, quad);
                consume_l1(d, x1, c1, act, yrow);
            }
        }
        {
            float x2[80];
            #pragma unroll
            for (int q = 0; q < 20; ++q) *(float4*)&x2[4 * q] = *(const float4*)(xrow + 160 + 4 * q);
            for (int c2 = 0; c2 < 4; ++c2) {
                bwd_mm(80 + c2, wb, bh, dPw, d, lane, l15, quad);
                consume_l2(d, x2, c2, act, yrow);
            }
        }
    }
}

// ---------------------------------------------------------------------------
// MLP fwd+bwd (unchanged — proven correct).
// ---------------------------------------------------------------------------
__global__ __launch_bounds__(128) void mlp_kernel(
    const float* __restrict__ h, const float* __restrict__ A1,
    const float* __restrict__ A2, const float* __restrict__ a1t,
    const float* __restrict__ a2t, const float* __restrict__ a3t,
    const float* __restrict__ b1, const float* __restrict__ b2,
    const float* __restrict__ b3, const float* __restrict__ dg2,
    float* __restrict__ xout, float* __restrict__ dhout, int n)
{
    __shared__ float hst[64][128];
    __shared__ unsigned short z1b[64][128];
    const int tid = threadIdx.x;
    const int s = blockIdx.x * 128 + tid;
    const bool act = s < n;
    #pragma unroll
    for (int q = 0; q < 16; ++q) {
        float4 v = make_float4(0.f, 0.f, 0.f, 0.f);
        if (act) v = ((const float4*)(h + (size_t)s * 64))[q];
        hst[4 * q + 0][tid] = v.x; hst[4 * q + 1][tid] = v.y;
        hst[4 * q + 2][tid] = v.z; hst[4 * q + 3][tid] = v.w;
    }
    float acc[64];
    #pragma unroll
    for (int k = 0; k < 64; ++k) acc[k] = b1[k];
    #pragma unroll 4
    for (int j = 0; j < 64; ++j) {
        float hj = hst[j][tid];
        const float* r = a1t + j * 64;
        #pragma unroll
        for (int k = 0; k < 64; ++k) acc[k] += hj * r[k];
    }
    #pragma unroll
    for (int k = 0; k < 64; ++k) {
        float z = acc[k];
        z1b[k][tid] = f2bf(z);
        float sg = 1.f / (1.f + __expf(-z));
        hst[k][tid] = z * sg;
    }
    #pragma unroll
    for (int k = 0; k < 64; ++k) acc[k] = b2[k];
    #pragma unroll 4
    for (int j = 0; j < 64; ++j) {
        float gj = hst[j][tid];
        const float* r = a2t + j * 64;
        #pragma unroll
        for (int k = 0; k < 64; ++k) acc[k] += gj * r[k];
    }
    float z2r[64];
    #pragma unroll
    for (int k = 0; k < 64; ++k) {
        z2r[k] = acc[k];
        float sg = 1.f / (1.f + __expf(-acc[k]));
        hst[k][tid] = acc[k] * sg;
    }
    #pragma unroll
    for (int k = 0; k < 64; ++k) acc[k] = b3[k];
    #pragma unroll 4
    for (int j = 0; j < 64; ++j) {
        float gj = hst[j][tid];
        const float* r = a3t + j * 64;
        #pragma unroll
        for (int k = 0; k < 64; ++k) acc[k] += gj * r[k];
    }
    if (act) {
        float4* xo = (float4*)(xout + (size_t)s * 64);
        #pragma unroll
        for (int q = 0; q < 16; ++q)
            xo[q] = make_float4(acc[4 * q], acc[4 * q + 1], acc[4 * q + 2], acc[4 * q + 3]);
    }
    #pragma unroll
    for (int k = 0; k < 64; ++k) {
        float z = z2r[k];
        float sg = 1.f / (1.f + __expf(-z));
        hst[k][tid] = dg2[k] * sg * (1.f + z * (1.f - sg));
    }
    #pragma unroll
    for (int j = 0; j < 64; ++j) acc[j] = 0.f;
    #pragma unroll 4
    for (int k = 0; k < 64; ++k) {
        float dd = hst[k][tid];
        const float* r = A2 + k * 64;
        #pragma unroll
        for (int j = 0; j < 64; ++j) acc[j] += dd * r[j];
    }
    #pragma unroll
    for (int j = 0; j < 64; ++j) {
        float z = __uint_as_float(((unsigned)z1b[j][tid]) << 16);
        float sg = 1.f / (1.f + __expf(-z));
        hst[j][tid] = acc[j] * sg * (1.f + z * (1.f - sg));
    }
    #pragma unroll
    for (int j = 0; j < 64; ++j) acc[j] = 0.f;
    #pragma unroll 4
    for (int k = 0; k < 64; ++k) {
        float dd = hst[k][tid];
        const float* r = A1 + k * 64;
        #pragma unroll
        for (int j = 0; j < 64; ++j) acc[j] += dd * r[j];
    }
    if (act) {
        float4* dho = (float4*)(dhout + (size_t)s * 64);
        #pragma unroll
        for (int q = 0; q < 16; ++q)
            dho[q] = make_float4(acc[4 * q], acc[4 * q + 1], acc[4 * q + 2], acc[4 * q + 3]);
    }
}

// ---------------------------------------------------------------------------
extern "C" void kernel_launch(void* const* d_in, const int* in_sizes, int n_in,
                              void* d_out, int out_size, void* d_ws, size_t ws_size,
                              hipStream_t stream)
{
    const float* tin = (const float*)d_in[0];
    const float* W0  = (const float*)d_in[1];
    const float* W1  = (const float*)d_in[2];
    const float* W2  = (const float*)d_in[3];
    const float* A1  = (const float*)d_in[4];
    const float* b1  = (const float*)d_in[5];
    const float* A2  = (const float*)d_in[6];
    const float* b2  = (const float*)d_in[7];
    const float* A3  = (const float*)d_in[8];
    const float* b3  = (const float*)d_in[9];
    float* out = (float*)d_out;
    char* ws   = (char*)d_ws;
    const int n = in_sizes[0] / IRR;

    unsigned short* wtf = (unsigned short*)(ws + B_WTF);
    unsigned short* wb  = (unsigned short*)(ws + B_WB);
    float* a1t  = (float*)(ws + B_A1T);
    float* a2t  = (float*)(ws + B_A2T);
    float* a3t  = (float*)(ws + B_A3T);
    float* dg2  = (float*)(ws + B_DG2);
    float* h    = (float*)(ws + B_H);
    float* dh   = h + (size_t)n * 64;
    float* xout = out;
    float* yout = out + (size_t)n * 64;

    const int total_prep = 64 * NP + 5376 * 64 + 3 * 4096 + 64;
    prep_kernel<<<(total_prep + 255) / 256, 256, 0, stream>>>(W0, W1, W2, A1, A2, A3,
                                                              wtf, wb, a1t, a2t, a3t, dg2);
    const int nb64 = (n + 63) / 64;
    fctp_fwd<<<nb64, 256, 0, stream>>>(tin, wtf, h, n);
    mlp_kernel<<<(n + 127) / 128, 128, 0, stream>>>(h, A1, A2, a1t, a2t, a3t,
                                                    b1, b2, b3, dg2, xout, dh, n);
    fctp_bwd<<<nb64, 256, 0, stream>>>(tin, wb, dh, yout, n);
}